// Round 8
// baseline (1495.736 us; speedup 1.0000x reference)
//
#include <hip/hip_runtime.h>

// Problem constants
#define NB   64      // batch
#define CIN  8
#define LIN  8192
#define L1N  4096    // conv1 out length
#define T2   2048    // conv2 out length (time steps)
#define ENC  64
#define NK   128     // codebook size
#define CD   64      // code dim
#define G3   192     // 3*ENC

// d_out layout (floats): quant_z [64*2048*64] | pred [64*2048*64] | codes [64*2048]
#define QOFF 0
#define POFF 8388608
#define COFF 16777216

// ws layout (floats): cnorm[128] @0 | PC[128*192] @128 | codes_i[131072] (int) @24704
#define PCOFF 128
#define CIOFF 24704

typedef _Float16 half2v __attribute__((ext_vector_type(2)));

__device__ __forceinline__ float sigf(float x) {
  float e = __builtin_amdgcn_exp2f(-1.4426950408889634f * x);
  return __builtin_amdgcn_rcpf(1.0f + e);
}
__device__ __forceinline__ float tanhf_fast(float x) {
  float e = __builtin_amdgcn_exp2f(2.8853900817779268f * x);
  return 1.0f - 2.0f * __builtin_amdgcn_rcpf(e + 1.0f);
}
__device__ __forceinline__ float rlane(float v, int k) {
  return __int_as_float(__builtin_amdgcn_readlane(__float_as_int(v), k));
}
__device__ __forceinline__ half2v as_h2(float v) { return __builtin_bit_cast(half2v, v); }

// ---------------- K0: prep = codebook norms (block 128) + PC table (blocks 0..127) ----------------
__global__ __launch_bounds__(192) void prep_kernel(const float* __restrict__ cb,
                                                   const float* __restrict__ w_ih,
                                                   const float* __restrict__ b_ih,
                                                   float* __restrict__ cnorm,
                                                   float* __restrict__ PC) {
  int blk = blockIdx.x;
  int j = threadIdx.x;
  if (blk == 128) {
    if (j < 128) {
      const float4* r = (const float4*)(cb + j * CD);
      float s0 = 0.f, s1 = 0.f, s2 = 0.f, s3 = 0.f;
#pragma unroll
      for (int q = 0; q < 16; q += 4) {
        float4 a = r[q], b = r[q + 1], cc = r[q + 2], d = r[q + 3];
        s0 += a.x * a.x + a.y * a.y + a.z * a.z + a.w * a.w;
        s1 += b.x * b.x + b.y * b.y + b.z * b.z + b.w * b.w;
        s2 += cc.x * cc.x + cc.y * cc.y + cc.z * cc.z + cc.w * cc.w;
        s3 += d.x * d.x + d.y * d.y + d.z * d.z + d.w * d.w;
      }
      cnorm[j] = (s0 + s1) + (s2 + s3);
    }
    return;
  }
  int c = blk;
  const float4* wp = (const float4*)(w_ih + j * ENC);
  const float4* cp = (const float4*)(cb + c * CD);
  float a0 = b_ih[j], a1 = 0.f, a2 = 0.f, a3 = 0.f;
#pragma unroll
  for (int q = 0; q < 16; q += 4) {
    float4 w0 = wp[q], c0 = cp[q];
    float4 w1 = wp[q + 1], c1 = cp[q + 1];
    float4 w2 = wp[q + 2], c2 = cp[q + 2];
    float4 w3 = wp[q + 3], c3 = cp[q + 3];
    a0 += w0.x * c0.x + w0.y * c0.y + w0.z * c0.z + w0.w * c0.w;
    a1 += w1.x * c1.x + w1.y * c1.y + w1.z * c1.z + w1.w * c1.w;
    a2 += w2.x * c2.x + w2.y * c2.y + w2.z * c2.z + w2.w * c2.w;
    a3 += w3.x * c3.x + w3.y * c3.y + w3.z * c3.z + w3.w * c3.w;
  }
  PC[c * G3 + j] = (a0 + a1) + (a2 + a3);
}

// ---------------- K1: FUSED conv1 + relu + conv2 + relu + VQ argmin + gather ----------------
// y1 never touches HBM: each block recomputes its y1 window [32 ci][2t0-4 .. 2t0+132) from an
// x-tile (8 x 280) staged in LDS. Phase B replicates conv1's accumulation order exactly
// (bias, then ci, then k) -> y1 values bit-identical to the unfused version; phase C (conv2)
// and the quant phase are unchanged -> codes exact. Kills y1's 32MB write + 32MB read + launch.
__global__ __launch_bounds__(256) void conv12q_kernel(const float* __restrict__ x,
                                                      const float* __restrict__ w1,
                                                      const float* __restrict__ b1,
                                                      const float* __restrict__ w2,
                                                      const float* __restrict__ b2,
                                                      const float* __restrict__ cb,
                                                      const float* __restrict__ cnorm,
                                                      float* __restrict__ quant,
                                                      float* __restrict__ codes_f,
                                                      int* __restrict__ codes_i) {
  __shared__ float sw2[32 * 5 * 64];   // 40960 B
  __shared__ float sw1[1280];          //  5120 B
  __shared__ float sxx[8][280];        //  8960 B
  __shared__ float sy[32][136];        // 17408 B
  __shared__ float sz[64][64];         // 16384 B   (total 88832 B)
  int b = blockIdx.x >> 5;
  int t0 = (blockIdx.x & 31) * 64;
  int tid = threadIdx.x;

  // ---- phase A: stage x-tile, conv1 weights, conv2 weights ----
  for (int i = tid; i < 32 * 5 * 64; i += 256) {
    int co = i & 63, r = i >> 6;
    sw2[i] = w2[co * 160 + r];
  }
  for (int i = tid; i < 1280; i += 256) sw1[i] = w1[i];
  {
    const float* xb = x + b * CIN * LIN;
    int X0 = 4 * t0 - 10;
    for (int i = tid; i < 8 * 280; i += 256) {
      int ci = i / 280, xo = i - ci * 280;
      int xi = X0 + xo;
      sxx[ci][xo] = ((unsigned)xi < (unsigned)LIN) ? xb[ci * LIN + xi] : 0.f;
    }
  }
  __syncthreads();

  // ---- phase B: y1 window (conv1+relu), exact conv1 accumulation order ----
  {
    int co = tid >> 3, sub = tid & 7;        // co in [0,32), 17 contiguous u's per thread
    float bias = b1[co];
    float wk1[8][5];
#pragma unroll
    for (int ci = 0; ci < 8; ci++)
#pragma unroll
      for (int k = 0; k < 5; k++) wk1[ci][k] = sw1[(co * 8 + ci) * 5 + k];
    float xv[8][38];
#pragma unroll
    for (int ci = 0; ci < 8; ci++) {
      const float2* s2 = (const float2*)(&sxx[ci][34 * sub]);
#pragma unroll
      for (int q = 0; q < 19; q++) {
        float2 v = s2[q];
        xv[ci][2 * q] = v.x; xv[ci][2 * q + 1] = v.y;
      }
    }
#pragma unroll
    for (int jj = 0; jj < 17; jj++) {
      int u = 17 * sub + jj;
      int p = 2 * t0 - 4 + u;                 // y1 position
      float a = bias;
#pragma unroll
      for (int ci = 0; ci < 8; ci++) {
#pragma unroll
        for (int k = 0; k < 5; k++) a = fmaf(xv[ci][2 * jj + k], wk1[ci][k], a);
      }
      sy[co][u] = ((unsigned)p < (unsigned)L1N) ? fmaxf(a, 0.f) : 0.f;
    }
  }
  __syncthreads();

  // ---- phase C: conv2 + relu into sz (identical to the unfused conv2) ----
  int co = tid & 63, ts = tid >> 6;
  {
    float acc[16];
    float bb = b2[co];
#pragma unroll
    for (int i = 0; i < 16; i++) acc[i] = bb;
    for (int ci = 0; ci < 32; ci++) {
      float xr[40];
      const float4* sx4 = (const float4*)(&sy[ci][32 * ts]);
#pragma unroll
      for (int q = 0; q < 10; q++) {
        float4 v = sx4[q];
        xr[4 * q] = v.x; xr[4 * q + 1] = v.y; xr[4 * q + 2] = v.z; xr[4 * q + 3] = v.w;
      }
      float wk[5];
#pragma unroll
      for (int k = 0; k < 5; k++) wk[k] = sw2[(ci * 5 + k) * 64 + co];
#pragma unroll
      for (int i = 0; i < 16; i++) {
#pragma unroll
        for (int k = 0; k < 5; k++) acc[i] = fmaf(xr[2 * i + k + 2], wk[k], acc[i]);
      }
    }
#pragma unroll
    for (int i = 0; i < 16; i++) sz[ts * 16 + i][co] = fmaxf(acc[i], 0.f);
  }
  __syncthreads();

  // ---- quant phase (unchanged) ----
  int lane = co, wave = ts;
  float4 ca[16], cq[16];
  {
    const float4* pa = (const float4*)(cb + lane * CD);
    const float4* pb = (const float4*)(cb + (64 + lane) * CD);
#pragma unroll
    for (int q = 0; q < 16; q++) { ca[q] = pa[q]; cq[q] = pb[q]; }
  }
  float cn0 = cnorm[lane], cn1 = cnorm[64 + lane];
  int vg0 = b * T2 + t0 + wave * 16;
  for (int i = 0; i < 16; i++) {
    int vl = wave * 16 + i;
    int v = vg0 + i;
    float d00 = 0.f, d01 = 0.f, d02 = 0.f, d03 = 0.f;
    float d10 = 0.f, d11 = 0.f, d12 = 0.f, d13 = 0.f;
#pragma unroll
    for (int q = 0; q < 16; q++) {
      float4 zq = *(const float4*)(&sz[vl][4 * q]);   // broadcast read, conflict-free
      d00 = fmaf(ca[q].x, zq.x, d00); d01 = fmaf(ca[q].y, zq.y, d01);
      d02 = fmaf(ca[q].z, zq.z, d02); d03 = fmaf(ca[q].w, zq.w, d03);
      d10 = fmaf(cq[q].x, zq.x, d10); d11 = fmaf(cq[q].y, zq.y, d11);
      d12 = fmaf(cq[q].z, zq.z, d12); d13 = fmaf(cq[q].w, zq.w, d13);
    }
    float s0 = cn0 - 2.f * ((d00 + d01) + (d02 + d03));
    float s1 = cn1 - 2.f * ((d10 + d11) + (d12 + d13));
    float sc; int idx;
    if (s1 < s0) { sc = s1; idx = 64 + lane; } else { sc = s0; idx = lane; }
#pragma unroll
    for (int m = 1; m < 64; m <<= 1) {
      float os = __shfl_xor(sc, m);
      int oi = __shfl_xor(idx, m);
      if (os < sc || (os == sc && oi < idx)) { sc = os; idx = oi; }
    }
    if (lane == 0) { codes_f[v] = (float)idx; codes_i[v] = idx; }
    quant[v * 64 + lane] = cb[idx * 64 + lane];
  }
}

// ---------------- K5: GRU scan — single wave/batch, ALL loop traffic in LDS (proven 827us) ----------------
// Single-wave f16-dot2 MV with every per-step global access removed: PC table (96 KB) + this
// batch's codes (8 KB) staged into LDS at startup, ctx output staged through a 16-row LDS ring
// flushed as 4x dwordx4 every 16 steps. Steady-state loop: zero global loads, 0.25 stores/step.
__global__ __attribute__((amdgpu_flat_work_group_size(64, 64), amdgpu_waves_per_eu(1, 1)))
void gru_kernel(const float* __restrict__ PC,
                const int* __restrict__ codes_i,
                const float* __restrict__ w_hh,
                const float* __restrict__ b_hh,
                float* __restrict__ ctx) {
  __shared__ float pcl[NK * G3];     // 98304 B
  __shared__ int   cpl[T2];          //  8192 B
  __shared__ float hring[16][64];    //  4096 B
  int b = blockIdx.x;
  int lane = threadIdx.x;

  // stage this batch's codes
  {
    const int4* src = (const int4*)(codes_i + b * T2);
    int4* dst = (int4*)cpl;
    for (int f = lane; f < T2 / 4; f += 64) dst[f] = src[f];
  }
  // stage the PC table
  {
    const float4* src = (const float4*)PC;
    float4* dst = (float4*)pcl;
    for (int f = lane; f < NK * G3 / 4; f += 64) dst[f] = src[f];
  }

  // W_hh rows lane / 64+lane / 128+lane as f16 pairs (96 VGPRs)
  half2v wr[32], wz[32], wn[32];
  {
    const float2* p0 = (const float2*)(w_hh + lane * ENC);
    const float2* p1 = (const float2*)(w_hh + (64 + lane) * ENC);
    const float2* p2 = (const float2*)(w_hh + (128 + lane) * ENC);
#pragma unroll
    for (int m = 0; m < 32; m++) {
      float2 a = p0[m]; wr[m] = (half2v){(_Float16)a.x, (_Float16)a.y};
      float2 c = p1[m]; wz[m] = (half2v){(_Float16)c.x, (_Float16)c.y};
      float2 d = p2[m]; wn[m] = (half2v){(_Float16)d.x, (_Float16)d.y};
    }
  }
  float br = b_hh[lane], bz = b_hh[64 + lane], bn = b_hh[128 + lane];

  float hreg = 0.f;
  int lane2a = 2 * lane, lane2b = 2 * lane + 1;  // shuffle sources (loop-invariant)
  const int cmax = T2 - 1;
  // single wave: staging ds_writes and these ds_reads are in-order in the DS pipe; the
  // compiler's lgkmcnt waits on the read results give the needed ordering (no barrier).
  int c2 = cpl[2];
  float xr0, xz0, xn0, xr1, xz1, xn1;
  {
    int c0 = cpl[0], c1 = cpl[1];
    const float* g = pcl + c0 * G3;
    xr0 = g[lane]; xz0 = g[64 + lane]; xn0 = g[128 + lane];
    g = pcl + c1 * G3;
    xr1 = g[lane]; xz1 = g[64 + lane]; xn1 = g[128 + lane];
  }
  float* cbase = ctx + (size_t)b * T2 * ENC;
#pragma unroll 1
  for (int t = 0; t < T2; t++) {
    const float* g = pcl + c2 * G3;                 // x for step t+2 (LDS, conflict-free)
    float xr2 = g[lane], xz2 = g[64 + lane], xn2 = g[128 + lane];
    int tn = t + 3; if (tn > cmax) tn = cmax;
    c2 = cpl[tn];                                   // uniform index -> LDS broadcast
    // pack h into f16 pairs: lane m (m<32) holds (h[2m], h[2m+1])
    float he = __shfl(hreg, lane2a);
    float ho = __shfl(hreg, lane2b);
    half2v hp2 = {(_Float16)he, (_Float16)ho};
    float hpk = __builtin_bit_cast(float, hp2);
    float fr0 = br, fr1 = 0.f, fr2 = 0.f, fr3 = 0.f;
    float fz0 = bz, fz1 = 0.f, fz2 = 0.f, fz3 = 0.f;
    float fn0 = bn, fn1 = 0.f, fn2 = 0.f, fn3 = 0.f;
#define MV(q) { \
    float s0 = rlane(hpk, 4 * (q) + 0); float s1 = rlane(hpk, 4 * (q) + 1); \
    float s2 = rlane(hpk, 4 * (q) + 2); float s3 = rlane(hpk, 4 * (q) + 3); \
    fr0 = __builtin_amdgcn_fdot2(wr[4 * (q) + 0], as_h2(s0), fr0, false); \
    fr1 = __builtin_amdgcn_fdot2(wr[4 * (q) + 1], as_h2(s1), fr1, false); \
    fr2 = __builtin_amdgcn_fdot2(wr[4 * (q) + 2], as_h2(s2), fr2, false); \
    fr3 = __builtin_amdgcn_fdot2(wr[4 * (q) + 3], as_h2(s3), fr3, false); \
    fz0 = __builtin_amdgcn_fdot2(wz[4 * (q) + 0], as_h2(s0), fz0, false); \
    fz1 = __builtin_amdgcn_fdot2(wz[4 * (q) + 1], as_h2(s1), fz1, false); \
    fz2 = __builtin_amdgcn_fdot2(wz[4 * (q) + 2], as_h2(s2), fz2, false); \
    fz3 = __builtin_amdgcn_fdot2(wz[4 * (q) + 3], as_h2(s3), fz3, false); \
    fn0 = __builtin_amdgcn_fdot2(wn[4 * (q) + 0], as_h2(s0), fn0, false); \
    fn1 = __builtin_amdgcn_fdot2(wn[4 * (q) + 1], as_h2(s1), fn1, false); \
    fn2 = __builtin_amdgcn_fdot2(wn[4 * (q) + 2], as_h2(s2), fn2, false); \
    fn3 = __builtin_amdgcn_fdot2(wn[4 * (q) + 3], as_h2(s3), fn3, false); }
    MV(0) MV(1) MV(2) MV(3) MV(4) MV(5) MV(6) MV(7)
#undef MV
    float ghr = (fr0 + fr1) + (fr2 + fr3);
    float ghz = (fz0 + fz1) + (fz2 + fz3);
    float ghn = (fn0 + fn1) + (fn2 + fn3);
    float r = sigf(xr0 + ghr);
    float zg = sigf(xz0 + ghz);
    float n = tanhf_fast(xn0 + r * ghn);
    hreg = fmaf(zg, hreg - n, n);
    hring[t & 15][lane] = hreg;
    if ((t & 15) == 15) {
      // flush 16 steps: 1024 floats = 4 float4 per lane, wide coalesced stores
#pragma unroll
      for (int q = 0; q < 4; q++) {
        int f = lane + 64 * q;
        int tr = f >> 4;
        int c4 = (f & 15) * 4;
        float4 v = *(const float4*)(&hring[tr][c4]);
        *(float4*)(cbase + (size_t)(t - 15 + tr) * ENC + c4) = v;
      }
    }
    xr0 = xr1; xz0 = xz1; xn0 = xn1;
    xr1 = xr2; xz1 = xz2; xn1 = xn2;
  }
}

// ---------------- K6: pred = ctx @ proj_w^T + proj_b (in-place on the ctx/pred slot) ----------------
__global__ void proj_kernel(const float* __restrict__ proj_w, const float* __restrict__ proj_b,
                            float* __restrict__ predio) {
  __shared__ float sc[64 * 64];
  int vbase = blockIdx.x * 64;
  int tid = threadIdx.x;
  int j = tid & 63, s = tid >> 6;
  for (int i = tid; i < 4096; i += 256) sc[i] = predio[vbase * 64 + i];
  __syncthreads();
  float4 w[16];
  const float4* wr = (const float4*)(proj_w + j * ENC);
#pragma unroll
  for (int q = 0; q < 16; q++) w[q] = wr[q];
  float bias = proj_b[j];
  float out[16];
#pragma unroll 4
  for (int i = 0; i < 16; i++) {
    const float4* c4 = (const float4*)(&sc[(s * 16 + i) * 64]);
    float a0 = bias, a1 = 0.f, a2 = 0.f, a3 = 0.f;
#pragma unroll
    for (int q = 0; q < 16; q += 4) {
      float4 ha = c4[q], hb = c4[q + 1], hc = c4[q + 2], hd = c4[q + 3];
      a0 += ha.x * w[q].x + ha.y * w[q].y + ha.z * w[q].z + ha.w * w[q].w;
      a1 += hb.x * w[q + 1].x + hb.y * w[q + 1].y + hb.z * w[q + 1].z + hb.w * w[q + 1].w;
      a2 += hc.x * w[q + 2].x + hc.y * w[q + 2].y + hc.z * w[q + 2].z + hc.w * w[q + 2].w;
      a3 += hd.x * w[q + 3].x + hd.y * w[q + 3].y + hd.z * w[q + 3].z + hd.w * w[q + 3].w;
    }
    out[i] = (a0 + a1) + (a2 + a3);
  }
#pragma unroll
  for (int i = 0; i < 16; i++) predio[(vbase + s * 16 + i) * 64 + j] = out[i];
}

extern "C" void kernel_launch(void* const* d_in, const int* in_sizes, int n_in,
                              void* d_out, int out_size, void* d_ws, size_t ws_size,
                              hipStream_t stream) {
  const float* x        = (const float*)d_in[0];
  const float* conv1_w  = (const float*)d_in[1];
  const float* conv1_b  = (const float*)d_in[2];
  const float* conv2_w  = (const float*)d_in[3];
  const float* conv2_b  = (const float*)d_in[4];
  const float* codebook = (const float*)d_in[5];
  const float* gru_w_ih = (const float*)d_in[6];
  const float* gru_w_hh = (const float*)d_in[7];
  const float* gru_b_ih = (const float*)d_in[8];
  const float* gru_b_hh = (const float*)d_in[9];
  const float* proj_w   = (const float*)d_in[10];
  const float* proj_b   = (const float*)d_in[11];

  float* out = (float*)d_out;
  float* quant = out + QOFF;     // quant_z output
  float* predz = out + POFF;     // ctx, then pred (in-place)
  float* codes_f = out + COFF;

  float* ws = (float*)d_ws;      // needs ~620 KB
  float* cnorm = ws;
  float* PC = ws + PCOFF;        // [128][192]
  int* codes_i = (int*)(ws + CIOFF);

  prep_kernel<<<129, 192, 0, stream>>>(codebook, gru_w_ih, gru_b_ih, cnorm, PC);
  conv12q_kernel<<<2048, 256, 0, stream>>>(x, conv1_w, conv1_b, conv2_w, conv2_b,
                                           codebook, cnorm, quant, codes_f, codes_i);
  gru_kernel<<<64, 64, 0, stream>>>(PC, codes_i, gru_w_hh, gru_b_hh, predz /* = ctx */);
  proj_kernel<<<2048, 256, 0, stream>>>(proj_w, proj_b, predz /* ctx -> pred in place */);
}

// Round 9
// 1118.639 us; speedup vs baseline: 1.3371x; 1.3371x over previous
//
#include <hip/hip_runtime.h>

// Problem constants
#define NB   64      // batch
#define CIN  8
#define LIN  8192
#define L1N  4096    // conv1 out length
#define T2   2048    // conv2 out length (time steps)
#define ENC  64
#define NK   128     // codebook size
#define CD   64      // code dim
#define G3   192     // 3*ENC

// d_out layout (floats): quant_z [64*2048*64] | pred [64*2048*64] | codes [64*2048]
#define QOFF 0
#define POFF 8388608
#define COFF 16777216

// ws layout (floats): cnorm[128] @0 | PC[128*192] @128 | codes_i[131072] (int) @24704
#define PCOFF 128
#define CIOFF 24704

typedef _Float16 half2v __attribute__((ext_vector_type(2)));

__device__ __forceinline__ float sigf(float x) {
  float e = __builtin_amdgcn_exp2f(-1.4426950408889634f * x);
  return __builtin_amdgcn_rcpf(1.0f + e);
}
__device__ __forceinline__ float tanhf_fast(float x) {
  float e = __builtin_amdgcn_exp2f(2.8853900817779268f * x);
  return 1.0f - 2.0f * __builtin_amdgcn_rcpf(e + 1.0f);
}
__device__ __forceinline__ float rlane(float v, int k) {
  return __int_as_float(__builtin_amdgcn_readlane(__float_as_int(v), k));
}
__device__ __forceinline__ half2v as_h2(float v) { return __builtin_bit_cast(half2v, v); }

// ---------------- K0: prep = codebook norms (block 128) + PC table (blocks 0..127) ----------------
__global__ __launch_bounds__(192) void prep_kernel(const float* __restrict__ cb,
                                                   const float* __restrict__ w_ih,
                                                   const float* __restrict__ b_ih,
                                                   float* __restrict__ cnorm,
                                                   float* __restrict__ PC) {
  int blk = blockIdx.x;
  int j = threadIdx.x;
  if (blk == 128) {
    if (j < 128) {
      const float4* r = (const float4*)(cb + j * CD);
      float s0 = 0.f, s1 = 0.f, s2 = 0.f, s3 = 0.f;
#pragma unroll
      for (int q = 0; q < 16; q += 4) {
        float4 a = r[q], b = r[q + 1], cc = r[q + 2], d = r[q + 3];
        s0 += a.x * a.x + a.y * a.y + a.z * a.z + a.w * a.w;
        s1 += b.x * b.x + b.y * b.y + b.z * b.z + b.w * b.w;
        s2 += cc.x * cc.x + cc.y * cc.y + cc.z * cc.z + cc.w * cc.w;
        s3 += d.x * d.x + d.y * d.y + d.z * d.z + d.w * d.w;
      }
      cnorm[j] = (s0 + s1) + (s2 + s3);
    }
    return;
  }
  int c = blk;
  const float4* wp = (const float4*)(w_ih + j * ENC);
  const float4* cp = (const float4*)(cb + c * CD);
  float a0 = b_ih[j], a1 = 0.f, a2 = 0.f, a3 = 0.f;
#pragma unroll
  for (int q = 0; q < 16; q += 4) {
    float4 w0 = wp[q], c0 = cp[q];
    float4 w1 = wp[q + 1], c1 = cp[q + 1];
    float4 w2 = wp[q + 2], c2 = cp[q + 2];
    float4 w3 = wp[q + 3], c3 = cp[q + 3];
    a0 += w0.x * c0.x + w0.y * c0.y + w0.z * c0.z + w0.w * c0.w;
    a1 += w1.x * c1.x + w1.y * c1.y + w1.z * c1.z + w1.w * c1.w;
    a2 += w2.x * c2.x + w2.y * c2.y + w2.z * c2.z + w2.w * c2.w;
    a3 += w3.x * c3.x + w3.y * c3.y + w3.z * c3.z + w3.w * c3.w;
  }
  PC[c * G3 + j] = (a0 + a1) + (a2 + a3);
}

// ---------------- K1: conv1 + relu  (x[64,8,8192] -> y1[64,32,4096]) ----------------
__global__ __launch_bounds__(256) void conv1_kernel(const float* __restrict__ x,
                                                    const float* __restrict__ w1,
                                                    const float* __restrict__ b1,
                                                    float* __restrict__ y1) {
  __shared__ float sw[1280];      // [co][ci][k] natural
  __shared__ float sx[8][136];    // u = xi - (2*t0-2), u in [0,131)
  int b = blockIdx.x >> 6;
  int t0 = (blockIdx.x & 63) * 64;
  int tid = threadIdx.x;
  for (int i = tid; i < 1280; i += 256) sw[i] = w1[i];
  const float* xb = x + b * CIN * LIN;
  for (int i = tid; i < 8 * 131; i += 256) {
    int ci = i / 131, u = i - ci * 131;
    int xi = 2 * t0 - 2 + u;
    sx[ci][u] = ((unsigned)xi < (unsigned)LIN) ? xb[ci * LIN + xi] : 0.f;
  }
  __syncthreads();
  int co = tid >> 3, tg = tid & 7;
  float bias = b1[co];
  float acc[8];
#pragma unroll
  for (int j = 0; j < 8; j++) acc[j] = bias;
#pragma unroll
  for (int ci = 0; ci < 8; ci++) {
    float xv[20];
    const float2* s2 = (const float2*)(&sx[ci][16 * tg]);
#pragma unroll
    for (int q = 0; q < 10; q++) {
      float2 v = s2[q];
      xv[2 * q] = v.x; xv[2 * q + 1] = v.y;
    }
    float wk[5];
#pragma unroll
    for (int k = 0; k < 5; k++) wk[k] = sw[(co * 8 + ci) * 5 + k];
#pragma unroll
    for (int j = 0; j < 8; j++) {
#pragma unroll
      for (int k = 0; k < 5; k++) acc[j] = fmaf(xv[2 * j + k], wk[k], acc[j]);
    }
  }
  float4* outp = (float4*)(y1 + (b * 32 + co) * L1N + t0 + tg * 8);
  float4 o0, o1;
  o0.x = fmaxf(acc[0], 0.f); o0.y = fmaxf(acc[1], 0.f);
  o0.z = fmaxf(acc[2], 0.f); o0.w = fmaxf(acc[3], 0.f);
  o1.x = fmaxf(acc[4], 0.f); o1.y = fmaxf(acc[5], 0.f);
  o1.z = fmaxf(acc[6], 0.f); o1.w = fmaxf(acc[7], 0.f);
  outp[0] = o0; outp[1] = o1;
}

// ---------------- K2: FUSED conv2 + relu + VQ argmin + gather (R7, proven) ----------------
__global__ __launch_bounds__(256) void conv2q_kernel(const float* __restrict__ y1,
                                                     const float* __restrict__ w2,
                                                     const float* __restrict__ b2,
                                                     const float* __restrict__ cb,
                                                     const float* __restrict__ cnorm,
                                                     float* __restrict__ quant,
                                                     float* __restrict__ codes_f,
                                                     int* __restrict__ codes_i) {
  __shared__ float sw[32 * 5 * 64];
  __shared__ float sx[32][136];
  __shared__ float sz[64][64];
  int b = blockIdx.x >> 5;
  int t0 = (blockIdx.x & 31) * 64;
  int tid = threadIdx.x;
  for (int i = tid; i < 32 * 5 * 64; i += 256) {
    int co = i & 63, r = i >> 6;
    sw[i] = w2[co * 160 + r];
  }
  for (int i = tid; i < 32 * 136; i += 256) {
    int ci = i / 136, u = i - ci * 136;
    int xi = 2 * t0 - 4 + u;
    float v = 0.f;
    if (xi >= 0 && xi < L1N) v = y1[(b * 32 + ci) * L1N + xi];
    sx[ci][u] = v;
  }
  __syncthreads();
  int co = tid & 63, ts = tid >> 6;
  float acc[16];
  float bb = b2[co];
#pragma unroll
  for (int i = 0; i < 16; i++) acc[i] = bb;
  for (int ci = 0; ci < 32; ci++) {
    float xr[40];
    const float4* sx4 = (const float4*)(&sx[ci][32 * ts]);
#pragma unroll
    for (int q = 0; q < 10; q++) {
      float4 v = sx4[q];
      xr[4 * q] = v.x; xr[4 * q + 1] = v.y; xr[4 * q + 2] = v.z; xr[4 * q + 3] = v.w;
    }
    float wk[5];
#pragma unroll
    for (int k = 0; k < 5; k++) wk[k] = sw[(ci * 5 + k) * 64 + co];
#pragma unroll
    for (int i = 0; i < 16; i++) {
#pragma unroll
      for (int k = 0; k < 5; k++) acc[i] = fmaf(xr[2 * i + k + 2], wk[k], acc[i]);
    }
  }
#pragma unroll
  for (int i = 0; i < 16; i++) sz[ts * 16 + i][co] = fmaxf(acc[i], 0.f);
  __syncthreads();

  // ---- quant phase ----
  int lane = co, wave = ts;
  float4 ca[16], cq[16];
  {
    const float4* pa = (const float4*)(cb + lane * CD);
    const float4* pb = (const float4*)(cb + (64 + lane) * CD);
#pragma unroll
    for (int q = 0; q < 16; q++) { ca[q] = pa[q]; cq[q] = pb[q]; }
  }
  float cn0 = cnorm[lane], cn1 = cnorm[64 + lane];
  int vg0 = b * T2 + t0 + wave * 16;
  for (int i = 0; i < 16; i++) {
    int vl = wave * 16 + i;
    int v = vg0 + i;
    float d00 = 0.f, d01 = 0.f, d02 = 0.f, d03 = 0.f;
    float d10 = 0.f, d11 = 0.f, d12 = 0.f, d13 = 0.f;
#pragma unroll
    for (int q = 0; q < 16; q++) {
      float4 zq = *(const float4*)(&sz[vl][4 * q]);   // broadcast read, conflict-free
      d00 = fmaf(ca[q].x, zq.x, d00); d01 = fmaf(ca[q].y, zq.y, d01);
      d02 = fmaf(ca[q].z, zq.z, d02); d03 = fmaf(ca[q].w, zq.w, d03);
      d10 = fmaf(cq[q].x, zq.x, d10); d11 = fmaf(cq[q].y, zq.y, d11);
      d12 = fmaf(cq[q].z, zq.z, d12); d13 = fmaf(cq[q].w, zq.w, d13);
    }
    float s0 = cn0 - 2.f * ((d00 + d01) + (d02 + d03));
    float s1 = cn1 - 2.f * ((d10 + d11) + (d12 + d13));
    float sc; int idx;
    if (s1 < s0) { sc = s1; idx = 64 + lane; } else { sc = s0; idx = lane; }
#pragma unroll
    for (int m = 1; m < 64; m <<= 1) {
      float os = __shfl_xor(sc, m);
      int oi = __shfl_xor(idx, m);
      if (os < sc || (os == sc && oi < idx)) { sc = os; idx = oi; }
    }
    if (lane == 0) { codes_f[v] = (float)idx; codes_i[v] = idx; }
    quant[v * 64 + lane] = cb[idx * 64 + lane];
  }
}

// ---------------- K5: FUSED GRU scan + projection — wave 0 scans, waves 1-3 project ----------------
// Wave 0 = the proven 827us single-wave f16-dot2 scan (all loop traffic in LDS), writing h into
// a double-buffered hring[2][16][64] instead of global ctx (ctx is NOT an output — only pred is).
// Waves 1-3 (idle SIMDs of the same CU) consume chunk c-1 while wave 0 computes chunk c: each
// lane holds proj_w row 'lane' in 64 VGPRs, reads h rows as broadcast float4, writes pred
// directly. One __syncthreads per 16-step chunk (128 total): wave 0 has NO global ops in its
// steady loop, so the barrier's vmcnt(0) drain is free for it; waves 1-3 finish each chunk in
// ~1K cyc vs wave 0's ~15K, so wave 0 never waits. Kills the proj kernel + 64 MB ctx traffic.
__global__ __attribute__((amdgpu_flat_work_group_size(256, 256), amdgpu_waves_per_eu(1, 1)))
void gruproj_kernel(const float* __restrict__ PC,
                    const int* __restrict__ codes_i,
                    const float* __restrict__ w_hh,
                    const float* __restrict__ b_hh,
                    const float* __restrict__ proj_w,
                    const float* __restrict__ proj_b,
                    float* __restrict__ pred) {
  __shared__ float pcl[NK * G3];       // 98304 B
  __shared__ int   cpl[T2];            //  8192 B
  __shared__ float hring[2][16][64];   //  8192 B  (total 114688 B)
  int b = blockIdx.x;
  int tid = threadIdx.x;
  int lane = tid & 63;
  int wq = tid >> 6;

  // stage this batch's codes + the PC table with all 256 threads
  {
    const int4* src = (const int4*)(codes_i + b * T2);
    int4* dst = (int4*)cpl;
    for (int f = tid; f < T2 / 4; f += 256) dst[f] = src[f];
    const float4* s2 = (const float4*)PC;
    float4* d2 = (float4*)pcl;
    for (int f = tid; f < NK * G3 / 4; f += 256) d2[f] = s2[f];
  }
  __syncthreads();

  // ---- per-role setup (wave-uniform branch) ----
  // wave 0: GRU state
  half2v wr[32], wz[32], wn[32];
  float br = 0.f, bz = 0.f, bn = 0.f;
  float hreg = 0.f;
  int c2 = 0;
  float xr0 = 0.f, xz0 = 0.f, xn0 = 0.f, xr1 = 0.f, xz1 = 0.f, xn1 = 0.f;
  // waves 1-3: proj state
  float4 w[16];
  float pbias = 0.f;

  if (wq == 0) {
    const float2* p0 = (const float2*)(w_hh + lane * ENC);
    const float2* p1 = (const float2*)(w_hh + (64 + lane) * ENC);
    const float2* p2 = (const float2*)(w_hh + (128 + lane) * ENC);
#pragma unroll
    for (int m = 0; m < 32; m++) {
      float2 a = p0[m]; wr[m] = (half2v){(_Float16)a.x, (_Float16)a.y};
      float2 c = p1[m]; wz[m] = (half2v){(_Float16)c.x, (_Float16)c.y};
      float2 d = p2[m]; wn[m] = (half2v){(_Float16)d.x, (_Float16)d.y};
    }
    br = b_hh[lane]; bz = b_hh[64 + lane]; bn = b_hh[128 + lane];
    c2 = cpl[2];
    int c0 = cpl[0], c1 = cpl[1];
    const float* g = pcl + c0 * G3;
    xr0 = g[lane]; xz0 = g[64 + lane]; xn0 = g[128 + lane];
    g = pcl + c1 * G3;
    xr1 = g[lane]; xz1 = g[64 + lane]; xn1 = g[128 + lane];
  } else {
    const float4* wp = (const float4*)(proj_w + lane * ENC);
#pragma unroll
    for (int q = 0; q < 16; q++) w[q] = wp[q];
    pbias = proj_b[lane];
  }

  int lane2a = 2 * lane, lane2b = 2 * lane + 1;  // shuffle sources (loop-invariant)
  const int cmax = T2 - 1;
  float* pbase = pred + (size_t)b * T2 * ENC + lane;

#pragma unroll 1
  for (int c = 0; c < 128; c++) {
    if (wq == 0) {
      // ---- 16 GRU steps into hring[c&1] ----
#pragma unroll 1
      for (int i = 0; i < 16; i++) {
        int t = c * 16 + i;
        const float* g = pcl + c2 * G3;             // x for step t+2 (LDS, conflict-free)
        float xr2 = g[lane], xz2 = g[64 + lane], xn2 = g[128 + lane];
        int tn = t + 3; if (tn > cmax) tn = cmax;
        c2 = cpl[tn];                               // uniform index -> LDS broadcast
        float he = __shfl(hreg, lane2a);
        float ho = __shfl(hreg, lane2b);
        half2v hp2 = {(_Float16)he, (_Float16)ho};
        float hpk = __builtin_bit_cast(float, hp2);
        float fr0 = br, fr1 = 0.f, fr2 = 0.f, fr3 = 0.f;
        float fz0 = bz, fz1 = 0.f, fz2 = 0.f, fz3 = 0.f;
        float fn0 = bn, fn1 = 0.f, fn2 = 0.f, fn3 = 0.f;
#define MV(q) { \
    float s0 = rlane(hpk, 4 * (q) + 0); float s1 = rlane(hpk, 4 * (q) + 1); \
    float s2 = rlane(hpk, 4 * (q) + 2); float s3 = rlane(hpk, 4 * (q) + 3); \
    fr0 = __builtin_amdgcn_fdot2(wr[4 * (q) + 0], as_h2(s0), fr0, false); \
    fr1 = __builtin_amdgcn_fdot2(wr[4 * (q) + 1], as_h2(s1), fr1, false); \
    fr2 = __builtin_amdgcn_fdot2(wr[4 * (q) + 2], as_h2(s2), fr2, false); \
    fr3 = __builtin_amdgcn_fdot2(wr[4 * (q) + 3], as_h2(s3), fr3, false); \
    fz0 = __builtin_amdgcn_fdot2(wz[4 * (q) + 0], as_h2(s0), fz0, false); \
    fz1 = __builtin_amdgcn_fdot2(wz[4 * (q) + 1], as_h2(s1), fz1, false); \
    fz2 = __builtin_amdgcn_fdot2(wz[4 * (q) + 2], as_h2(s2), fz2, false); \
    fz3 = __builtin_amdgcn_fdot2(wz[4 * (q) + 3], as_h2(s3), fz3, false); \
    fn0 = __builtin_amdgcn_fdot2(wn[4 * (q) + 0], as_h2(s0), fn0, false); \
    fn1 = __builtin_amdgcn_fdot2(wn[4 * (q) + 1], as_h2(s1), fn1, false); \
    fn2 = __builtin_amdgcn_fdot2(wn[4 * (q) + 2], as_h2(s2), fn2, false); \
    fn3 = __builtin_amdgcn_fdot2(wn[4 * (q) + 3], as_h2(s3), fn3, false); }
        MV(0) MV(1) MV(2) MV(3) MV(4) MV(5) MV(6) MV(7)
#undef MV
        float ghr = (fr0 + fr1) + (fr2 + fr3);
        float ghz = (fz0 + fz1) + (fz2 + fz3);
        float ghn = (fn0 + fn1) + (fn2 + fn3);
        float r = sigf(xr0 + ghr);
        float zg = sigf(xz0 + ghz);
        float n = tanhf_fast(xn0 + r * ghn);
        hreg = fmaf(zg, hreg - n, n);
        hring[c & 1][i][lane] = hreg;
        xr0 = xr1; xz0 = xz1; xn0 = xn1;
        xr1 = xr2; xz1 = xz2; xn1 = xn2;
      }
    } else if (c > 0) {
      // ---- project chunk c-1 from hring[(c-1)&1] ----
      int cc = c - 1, buf = cc & 1, tb = cc * 16;
#pragma unroll 1
      for (int t = wq - 1; t < 16; t += 3) {
        const float4* hrow = (const float4*)(&hring[buf][t][0]);   // broadcast reads
        float a0 = pbias, a1 = 0.f, a2 = 0.f, a3 = 0.f;
#pragma unroll
        for (int q = 0; q < 16; q += 4) {
          float4 ha = hrow[q], hb = hrow[q + 1], hc = hrow[q + 2], hd = hrow[q + 3];
          a0 += ha.x * w[q].x + ha.y * w[q].y + ha.z * w[q].z + ha.w * w[q].w;
          a1 += hb.x * w[q + 1].x + hb.y * w[q + 1].y + hb.z * w[q + 1].z + hb.w * w[q + 1].w;
          a2 += hc.x * w[q + 2].x + hc.y * w[q + 2].y + hc.z * w[q + 2].z + hc.w * w[q + 2].w;
          a3 += hd.x * w[q + 3].x + hd.y * w[q + 3].y + hd.z * w[q + 3].z + hd.w * w[q + 3].w;
        }
        pbase[(size_t)(tb + t) * ENC] = (a0 + a1) + (a2 + a3);
      }
    }
    __syncthreads();
  }
  // ---- final chunk 127 ----
  if (wq > 0) {
    int cc = 127, buf = cc & 1, tb = cc * 16;
#pragma unroll 1
    for (int t = wq - 1; t < 16; t += 3) {
      const float4* hrow = (const float4*)(&hring[buf][t][0]);
      float a0 = pbias, a1 = 0.f, a2 = 0.f, a3 = 0.f;
#pragma unroll
      for (int q = 0; q < 16; q += 4) {
        float4 ha = hrow[q], hb = hrow[q + 1], hc = hrow[q + 2], hd = hrow[q + 3];
        a0 += ha.x * w[q].x + ha.y * w[q].y + ha.z * w[q].z + ha.w * w[q].w;
        a1 += hb.x * w[q + 1].x + hb.y * w[q + 1].y + hb.z * w[q + 1].z + hb.w * w[q + 1].w;
        a2 += hc.x * w[q + 2].x + hc.y * w[q + 2].y + hc.z * w[q + 2].z + hc.w * w[q + 2].w;
        a3 += hd.x * w[q + 3].x + hd.y * w[q + 3].y + hd.z * w[q + 3].z + hd.w * w[q + 3].w;
      }
      pbase[(size_t)(tb + t) * ENC] = (a0 + a1) + (a2 + a3);
    }
  }
}

extern "C" void kernel_launch(void* const* d_in, const int* in_sizes, int n_in,
                              void* d_out, int out_size, void* d_ws, size_t ws_size,
                              hipStream_t stream) {
  const float* x        = (const float*)d_in[0];
  const float* conv1_w  = (const float*)d_in[1];
  const float* conv1_b  = (const float*)d_in[2];
  const float* conv2_w  = (const float*)d_in[3];
  const float* conv2_b  = (const float*)d_in[4];
  const float* codebook = (const float*)d_in[5];
  const float* gru_w_ih = (const float*)d_in[6];
  const float* gru_w_hh = (const float*)d_in[7];
  const float* gru_b_ih = (const float*)d_in[8];
  const float* gru_b_hh = (const float*)d_in[9];
  const float* proj_w   = (const float*)d_in[10];
  const float* proj_b   = (const float*)d_in[11];

  float* out = (float*)d_out;
  float* quant = out + QOFF;     // quant_z output
  float* predz = out + POFF;     // y1 lives here first, then pred (y1 dead before gruproj)
  float* codes_f = out + COFF;

  float* ws = (float*)d_ws;      // needs ~620 KB
  float* cnorm = ws;
  float* PC = ws + PCOFF;        // [128][192]
  int* codes_i = (int*)(ws + CIOFF);

  prep_kernel<<<129, 192, 0, stream>>>(codebook, gru_w_ih, gru_b_ih, cnorm, PC);
  conv1_kernel<<<4096, 256, 0, stream>>>(x, conv1_w, conv1_b, predz /* = y1 (8M floats exactly) */);
  conv2q_kernel<<<2048, 256, 0, stream>>>(predz /* y1 */, conv2_w, conv2_b, codebook, cnorm,
                                          quant, codes_f, codes_i);
  gruproj_kernel<<<64, 256, 0, stream>>>(PC, codes_i, gru_w_hh, gru_b_hh, proj_w, proj_b,
                                         predz /* = pred (y1 dead) */);
}

// Round 10
// 1101.429 us; speedup vs baseline: 1.3580x; 1.0156x over previous
//
#include <hip/hip_runtime.h>

// Problem constants
#define NB   64      // batch
#define CIN  8
#define LIN  8192
#define L1N  4096    // conv1 out length
#define T2   2048    // conv2 out length (time steps)
#define ENC  64
#define NK   128     // codebook size
#define CD   64      // code dim
#define G3   192     // 3*ENC

// d_out layout (floats): quant_z [64*2048*64] | pred [64*2048*64] | codes [64*2048]
#define QOFF 0
#define POFF 8388608
#define COFF 16777216

// ws layout (floats): cnorm[128] @0 | PC[128*192] @128 | codes_i[131072] (int) @24704
#define PCOFF 128
#define CIOFF 24704

typedef _Float16 half2v __attribute__((ext_vector_type(2)));

__device__ __forceinline__ float sigf(float x) {
  float e = __builtin_amdgcn_exp2f(-1.4426950408889634f * x);
  return __builtin_amdgcn_rcpf(1.0f + e);
}
__device__ __forceinline__ float tanhf_fast(float x) {
  float e = __builtin_amdgcn_exp2f(2.8853900817779268f * x);
  return 1.0f - 2.0f * __builtin_amdgcn_rcpf(e + 1.0f);
}
__device__ __forceinline__ float rlane(float v, int k) {
  return __int_as_float(__builtin_amdgcn_readlane(__float_as_int(v), k));
}
__device__ __forceinline__ half2v as_h2(float v) { return __builtin_bit_cast(half2v, v); }

// ---------------- K0: prep = codebook norms (block 128) + PC table (blocks 0..127) ----------------
__global__ __launch_bounds__(192) void prep_kernel(const float* __restrict__ cb,
                                                   const float* __restrict__ w_ih,
                                                   const float* __restrict__ b_ih,
                                                   float* __restrict__ cnorm,
                                                   float* __restrict__ PC) {
  int blk = blockIdx.x;
  int j = threadIdx.x;
  if (blk == 128) {
    if (j < 128) {
      const float4* r = (const float4*)(cb + j * CD);
      float s0 = 0.f, s1 = 0.f, s2 = 0.f, s3 = 0.f;
#pragma unroll
      for (int q = 0; q < 16; q += 4) {
        float4 a = r[q], b = r[q + 1], cc = r[q + 2], d = r[q + 3];
        s0 += a.x * a.x + a.y * a.y + a.z * a.z + a.w * a.w;
        s1 += b.x * b.x + b.y * b.y + b.z * b.z + b.w * b.w;
        s2 += cc.x * cc.x + cc.y * cc.y + cc.z * cc.z + cc.w * cc.w;
        s3 += d.x * d.x + d.y * d.y + d.z * d.z + d.w * d.w;
      }
      cnorm[j] = (s0 + s1) + (s2 + s3);
    }
    return;
  }
  int c = blk;
  const float4* wp = (const float4*)(w_ih + j * ENC);
  const float4* cp = (const float4*)(cb + c * CD);
  float a0 = b_ih[j], a1 = 0.f, a2 = 0.f, a3 = 0.f;
#pragma unroll
  for (int q = 0; q < 16; q += 4) {
    float4 w0 = wp[q], c0 = cp[q];
    float4 w1 = wp[q + 1], c1 = cp[q + 1];
    float4 w2 = wp[q + 2], c2 = cp[q + 2];
    float4 w3 = wp[q + 3], c3 = cp[q + 3];
    a0 += w0.x * c0.x + w0.y * c0.y + w0.z * c0.z + w0.w * c0.w;
    a1 += w1.x * c1.x + w1.y * c1.y + w1.z * c1.z + w1.w * c1.w;
    a2 += w2.x * c2.x + w2.y * c2.y + w2.z * c2.z + w2.w * c2.w;
    a3 += w3.x * c3.x + w3.y * c3.y + w3.z * c3.z + w3.w * c3.w;
  }
  PC[c * G3 + j] = (a0 + a1) + (a2 + a3);
}

// ---------------- K1: FUSED conv1 + relu + conv2 + relu + VQ argmin + gather ----------------
// y1 never touches HBM. Fixes vs the R8 attempt (which was correct but slow):
//  (a) phase B loops ci with unroll 1, reloading xv[38] per ci (~65 live VGPRs, conv1's proven
//      per-ci pattern) instead of holding xv[8][38]=304 floats -> no scratch spills;
//  (b) sxx and sz share one LDS buffer (sxx dead before phase C writes sz):
//      40960+5120+17408+16384 = 79872 B <= 81920 -> 2 blocks/CU (R8's 88.8KB halved occupancy).
// Phase B math identical to R8 (HW-verified: passed, codes exact); phases C/quant identical to
// the proven conv2q. Kills conv1's launch + 32MB y1 write + 32MB y1 read.
__global__ __launch_bounds__(256) void conv12q_kernel(const float* __restrict__ x,
                                                      const float* __restrict__ w1,
                                                      const float* __restrict__ b1,
                                                      const float* __restrict__ w2,
                                                      const float* __restrict__ b2,
                                                      const float* __restrict__ cb,
                                                      const float* __restrict__ cnorm,
                                                      float* __restrict__ quant,
                                                      float* __restrict__ codes_f,
                                                      int* __restrict__ codes_i) {
  __shared__ float sw2[32 * 5 * 64];     // 40960 B
  __shared__ float sw1[1280];            //  5120 B
  __shared__ float sy[32][136];          // 17408 B
  __shared__ float ubuf[4096];           // 16384 B : sxx[8][280] (phase A/B) then sz[64][64]
  float (*sxx)[280] = (float(*)[280])ubuf;
  float (*sz)[64]   = (float(*)[64])ubuf;
  int b = blockIdx.x >> 5;
  int t0 = (blockIdx.x & 31) * 64;
  int tid = threadIdx.x;

  // ---- phase A: stage x-tile + conv1 weights + conv2 weights ----
  for (int i = tid; i < 32 * 5 * 64; i += 256) {
    int co = i & 63, r = i >> 6;
    sw2[i] = w2[co * 160 + r];
  }
  for (int i = tid; i < 1280; i += 256) sw1[i] = w1[i];
  {
    const float* xb = x + b * CIN * LIN;
    int X0 = 4 * t0 - 10;
    for (int i = tid; i < 8 * 280; i += 256) {
      int ci = i / 280, xo = i - ci * 280;
      int xi = X0 + xo;
      sxx[ci][xo] = ((unsigned)xi < (unsigned)LIN) ? xb[ci * LIN + xi] : 0.f;
    }
  }
  __syncthreads();

  // ---- phase B: y1 window (conv1+relu), conv1's accumulation order (bias, ci, k) ----
  {
    int co1 = tid >> 3, sub = tid & 7;       // co1 in [0,32), 17 outputs per thread
    float acc1[17];
    float bias = b1[co1];
#pragma unroll
    for (int jj = 0; jj < 17; jj++) acc1[jj] = bias;
#pragma unroll 1
    for (int ci = 0; ci < 8; ci++) {
      float xv[38];
      const float2* s2 = (const float2*)(&sxx[ci][34 * sub]);
#pragma unroll
      for (int q = 0; q < 19; q++) {
        float2 v = s2[q];
        xv[2 * q] = v.x; xv[2 * q + 1] = v.y;
      }
      float wk1[5];
#pragma unroll
      for (int k = 0; k < 5; k++) wk1[k] = sw1[(co1 * 8 + ci) * 5 + k];
#pragma unroll
      for (int jj = 0; jj < 17; jj++) {
#pragma unroll
        for (int k = 0; k < 5; k++) acc1[jj] = fmaf(xv[2 * jj + k], wk1[k], acc1[jj]);
      }
    }
#pragma unroll
    for (int jj = 0; jj < 17; jj++) {
      int u = 17 * sub + jj;
      int p = 2 * t0 - 4 + u;                // y1 position
      sy[co1][u] = ((unsigned)p < (unsigned)L1N) ? fmaxf(acc1[jj], 0.f) : 0.f;
    }
  }
  __syncthreads();                            // sxx dead from here; ubuf becomes sz

  // ---- phase C: conv2 + relu into sz (identical to the proven conv2q) ----
  int co = tid & 63, ts = tid >> 6;
  {
    float acc[16];
    float bb = b2[co];
#pragma unroll
    for (int i = 0; i < 16; i++) acc[i] = bb;
    for (int ci = 0; ci < 32; ci++) {
      float xr[40];
      const float4* sx4 = (const float4*)(&sy[ci][32 * ts]);
#pragma unroll
      for (int q = 0; q < 10; q++) {
        float4 v = sx4[q];
        xr[4 * q] = v.x; xr[4 * q + 1] = v.y; xr[4 * q + 2] = v.z; xr[4 * q + 3] = v.w;
      }
      float wk[5];
#pragma unroll
      for (int k = 0; k < 5; k++) wk[k] = sw2[(ci * 5 + k) * 64 + co];
#pragma unroll
      for (int i = 0; i < 16; i++) {
#pragma unroll
        for (int k = 0; k < 5; k++) acc[i] = fmaf(xr[2 * i + k + 2], wk[k], acc[i]);
      }
    }
#pragma unroll
    for (int i = 0; i < 16; i++) sz[ts * 16 + i][co] = fmaxf(acc[i], 0.f);
  }
  __syncthreads();

  // ---- quant phase (identical to the proven conv2q) ----
  int lane = co, wave = ts;
  float4 ca[16], cq[16];
  {
    const float4* pa = (const float4*)(cb + lane * CD);
    const float4* pb = (const float4*)(cb + (64 + lane) * CD);
#pragma unroll
    for (int q = 0; q < 16; q++) { ca[q] = pa[q]; cq[q] = pb[q]; }
  }
  float cn0 = cnorm[lane], cn1 = cnorm[64 + lane];
  int vg0 = b * T2 + t0 + wave * 16;
  for (int i = 0; i < 16; i++) {
    int vl = wave * 16 + i;
    int v = vg0 + i;
    float d00 = 0.f, d01 = 0.f, d02 = 0.f, d03 = 0.f;
    float d10 = 0.f, d11 = 0.f, d12 = 0.f, d13 = 0.f;
#pragma unroll
    for (int q = 0; q < 16; q++) {
      float4 zq = *(const float4*)(&sz[vl][4 * q]);   // broadcast read, conflict-free
      d00 = fmaf(ca[q].x, zq.x, d00); d01 = fmaf(ca[q].y, zq.y, d01);
      d02 = fmaf(ca[q].z, zq.z, d02); d03 = fmaf(ca[q].w, zq.w, d03);
      d10 = fmaf(cq[q].x, zq.x, d10); d11 = fmaf(cq[q].y, zq.y, d11);
      d12 = fmaf(cq[q].z, zq.z, d12); d13 = fmaf(cq[q].w, zq.w, d13);
    }
    float s0 = cn0 - 2.f * ((d00 + d01) + (d02 + d03));
    float s1 = cn1 - 2.f * ((d10 + d11) + (d12 + d13));
    float sc; int idx;
    if (s1 < s0) { sc = s1; idx = 64 + lane; } else { sc = s0; idx = lane; }
#pragma unroll
    for (int m = 1; m < 64; m <<= 1) {
      float os = __shfl_xor(sc, m);
      int oi = __shfl_xor(idx, m);
      if (os < sc || (os == sc && oi < idx)) { sc = os; idx = oi; }
    }
    if (lane == 0) { codes_f[v] = (float)idx; codes_i[v] = idx; }
    quant[v * 64 + lane] = cb[idx * 64 + lane];
  }
}

// ---------------- K5: FUSED GRU scan + projection — wave 0 scans, waves 1-3 project (806us) ----------------
__global__ __attribute__((amdgpu_flat_work_group_size(256, 256), amdgpu_waves_per_eu(1, 1)))
void gruproj_kernel(const float* __restrict__ PC,
                    const int* __restrict__ codes_i,
                    const float* __restrict__ w_hh,
                    const float* __restrict__ b_hh,
                    const float* __restrict__ proj_w,
                    const float* __restrict__ proj_b,
                    float* __restrict__ pred) {
  __shared__ float pcl[NK * G3];       // 98304 B
  __shared__ int   cpl[T2];            //  8192 B
  __shared__ float hring[2][16][64];   //  8192 B  (total 114688 B)
  int b = blockIdx.x;
  int tid = threadIdx.x;
  int lane = tid & 63;
  int wq = tid >> 6;

  // stage this batch's codes + the PC table with all 256 threads
  {
    const int4* src = (const int4*)(codes_i + b * T2);
    int4* dst = (int4*)cpl;
    for (int f = tid; f < T2 / 4; f += 256) dst[f] = src[f];
    const float4* s2 = (const float4*)PC;
    float4* d2 = (float4*)pcl;
    for (int f = tid; f < NK * G3 / 4; f += 256) d2[f] = s2[f];
  }
  __syncthreads();

  // ---- per-role setup (wave-uniform branch) ----
  half2v wr[32], wz[32], wn[32];
  float br = 0.f, bz = 0.f, bn = 0.f;
  float hreg = 0.f;
  int c2 = 0;
  float xr0 = 0.f, xz0 = 0.f, xn0 = 0.f, xr1 = 0.f, xz1 = 0.f, xn1 = 0.f;
  float4 w[16];
  float pbias = 0.f;

  if (wq == 0) {
    const float2* p0 = (const float2*)(w_hh + lane * ENC);
    const float2* p1 = (const float2*)(w_hh + (64 + lane) * ENC);
    const float2* p2 = (const float2*)(w_hh + (128 + lane) * ENC);
#pragma unroll
    for (int m = 0; m < 32; m++) {
      float2 a = p0[m]; wr[m] = (half2v){(_Float16)a.x, (_Float16)a.y};
      float2 c = p1[m]; wz[m] = (half2v){(_Float16)c.x, (_Float16)c.y};
      float2 d = p2[m]; wn[m] = (half2v){(_Float16)d.x, (_Float16)d.y};
    }
    br = b_hh[lane]; bz = b_hh[64 + lane]; bn = b_hh[128 + lane];
    c2 = cpl[2];
    int c0 = cpl[0], c1 = cpl[1];
    const float* g = pcl + c0 * G3;
    xr0 = g[lane]; xz0 = g[64 + lane]; xn0 = g[128 + lane];
    g = pcl + c1 * G3;
    xr1 = g[lane]; xz1 = g[64 + lane]; xn1 = g[128 + lane];
  } else {
    const float4* wp = (const float4*)(proj_w + lane * ENC);
#pragma unroll
    for (int q = 0; q < 16; q++) w[q] = wp[q];
    pbias = proj_b[lane];
  }

  int lane2a = 2 * lane, lane2b = 2 * lane + 1;  // shuffle sources (loop-invariant)
  const int cmax = T2 - 1;
  float* pbase = pred + (size_t)b * T2 * ENC + lane;

#pragma unroll 1
  for (int c = 0; c < 128; c++) {
    if (wq == 0) {
      // ---- 16 GRU steps into hring[c&1] ----
#pragma unroll 1
      for (int i = 0; i < 16; i++) {
        int t = c * 16 + i;
        const float* g = pcl + c2 * G3;             // x for step t+2 (LDS, conflict-free)
        float xr2 = g[lane], xz2 = g[64 + lane], xn2 = g[128 + lane];
        int tn = t + 3; if (tn > cmax) tn = cmax;
        c2 = cpl[tn];                               // uniform index -> LDS broadcast
        float he = __shfl(hreg, lane2a);
        float ho = __shfl(hreg, lane2b);
        half2v hp2 = {(_Float16)he, (_Float16)ho};
        float hpk = __builtin_bit_cast(float, hp2);
        float fr0 = br, fr1 = 0.f, fr2 = 0.f, fr3 = 0.f;
        float fz0 = bz, fz1 = 0.f, fz2 = 0.f, fz3 = 0.f;
        float fn0 = bn, fn1 = 0.f, fn2 = 0.f, fn3 = 0.f;
#define MV(q) { \
    float s0 = rlane(hpk, 4 * (q) + 0); float s1 = rlane(hpk, 4 * (q) + 1); \
    float s2 = rlane(hpk, 4 * (q) + 2); float s3 = rlane(hpk, 4 * (q) + 3); \
    fr0 = __builtin_amdgcn_fdot2(wr[4 * (q) + 0], as_h2(s0), fr0, false); \
    fr1 = __builtin_amdgcn_fdot2(wr[4 * (q) + 1], as_h2(s1), fr1, false); \
    fr2 = __builtin_amdgcn_fdot2(wr[4 * (q) + 2], as_h2(s2), fr2, false); \
    fr3 = __builtin_amdgcn_fdot2(wr[4 * (q) + 3], as_h2(s3), fr3, false); \
    fz0 = __builtin_amdgcn_fdot2(wz[4 * (q) + 0], as_h2(s0), fz0, false); \
    fz1 = __builtin_amdgcn_fdot2(wz[4 * (q) + 1], as_h2(s1), fz1, false); \
    fz2 = __builtin_amdgcn_fdot2(wz[4 * (q) + 2], as_h2(s2), fz2, false); \
    fz3 = __builtin_amdgcn_fdot2(wz[4 * (q) + 3], as_h2(s3), fz3, false); \
    fn0 = __builtin_amdgcn_fdot2(wn[4 * (q) + 0], as_h2(s0), fn0, false); \
    fn1 = __builtin_amdgcn_fdot2(wn[4 * (q) + 1], as_h2(s1), fn1, false); \
    fn2 = __builtin_amdgcn_fdot2(wn[4 * (q) + 2], as_h2(s2), fn2, false); \
    fn3 = __builtin_amdgcn_fdot2(wn[4 * (q) + 3], as_h2(s3), fn3, false); }
        MV(0) MV(1) MV(2) MV(3) MV(4) MV(5) MV(6) MV(7)
#undef MV
        float ghr = (fr0 + fr1) + (fr2 + fr3);
        float ghz = (fz0 + fz1) + (fz2 + fz3);
        float ghn = (fn0 + fn1) + (fn2 + fn3);
        float r = sigf(xr0 + ghr);
        float zg = sigf(xz0 + ghz);
        float n = tanhf_fast(xn0 + r * ghn);
        hreg = fmaf(zg, hreg - n, n);
        hring[c & 1][i][lane] = hreg;
        xr0 = xr1; xz0 = xz1; xn0 = xn1;
        xr1 = xr2; xz1 = xz2; xn1 = xn2;
      }
    } else if (c > 0) {
      // ---- project chunk c-1 from hring[(c-1)&1] ----
      int cc = c - 1, buf = cc & 1, tb = cc * 16;
#pragma unroll 1
      for (int t = wq - 1; t < 16; t += 3) {
        const float4* hrow = (const float4*)(&hring[buf][t][0]);   // broadcast reads
        float a0 = pbias, a1 = 0.f, a2 = 0.f, a3 = 0.f;
#pragma unroll
        for (int q = 0; q < 16; q += 4) {
          float4 ha = hrow[q], hb = hrow[q + 1], hc = hrow[q + 2], hd = hrow[q + 3];
          a0 += ha.x * w[q].x + ha.y * w[q].y + ha.z * w[q].z + ha.w * w[q].w;
          a1 += hb.x * w[q + 1].x + hb.y * w[q + 1].y + hb.z * w[q + 1].z + hb.w * w[q + 1].w;
          a2 += hc.x * w[q + 2].x + hc.y * w[q + 2].y + hc.z * w[q + 2].z + hc.w * w[q + 2].w;
          a3 += hd.x * w[q + 3].x + hd.y * w[q + 3].y + hd.z * w[q + 3].z + hd.w * w[q + 3].w;
        }
        pbase[(size_t)(tb + t) * ENC] = (a0 + a1) + (a2 + a3);
      }
    }
    __syncthreads();
  }
  // ---- final chunk 127 ----
  if (wq > 0) {
    int cc = 127, buf = cc & 1, tb = cc * 16;
#pragma unroll 1
    for (int t = wq - 1; t < 16; t += 3) {
      const float4* hrow = (const float4*)(&hring[buf][t][0]);
      float a0 = pbias, a1 = 0.f, a2 = 0.f, a3 = 0.f;
#pragma unroll
      for (int q = 0; q < 16; q += 4) {
        float4 ha = hrow[q], hb = hrow[q + 1], hc = hrow[q + 2], hd = hrow[q + 3];
        a0 += ha.x * w[q].x + ha.y * w[q].y + ha.z * w[q].z + ha.w * w[q].w;
        a1 += hb.x * w[q + 1].x + hb.y * w[q + 1].y + hb.z * w[q + 1].z + hb.w * w[q + 1].w;
        a2 += hc.x * w[q + 2].x + hc.y * w[q + 2].y + hc.z * w[q + 2].z + hc.w * w[q + 2].w;
        a3 += hd.x * w[q + 3].x + hd.y * w[q + 3].y + hd.z * w[q + 3].z + hd.w * w[q + 3].w;
      }
      pbase[(size_t)(tb + t) * ENC] = (a0 + a1) + (a2 + a3);
    }
  }
}

extern "C" void kernel_launch(void* const* d_in, const int* in_sizes, int n_in,
                              void* d_out, int out_size, void* d_ws, size_t ws_size,
                              hipStream_t stream) {
  const float* x        = (const float*)d_in[0];
  const float* conv1_w  = (const float*)d_in[1];
  const float* conv1_b  = (const float*)d_in[2];
  const float* conv2_w  = (const float*)d_in[3];
  const float* conv2_b  = (const float*)d_in[4];
  const float* codebook = (const float*)d_in[5];
  const float* gru_w_ih = (const float*)d_in[6];
  const float* gru_w_hh = (const float*)d_in[7];
  const float* gru_b_ih = (const float*)d_in[8];
  const float* gru_b_hh = (const float*)d_in[9];
  const float* proj_w   = (const float*)d_in[10];
  const float* proj_b   = (const float*)d_in[11];

  float* out = (float*)d_out;
  float* quant = out + QOFF;     // quant_z output
  float* pred  = out + POFF;     // pred output (no intermediate ever lives here now)
  float* codes_f = out + COFF;

  float* ws = (float*)d_ws;      // needs ~620 KB
  float* cnorm = ws;
  float* PC = ws + PCOFF;        // [128][192]
  int* codes_i = (int*)(ws + CIOFF);

  prep_kernel<<<129, 192, 0, stream>>>(codebook, gru_w_ih, gru_b_ih, cnorm, PC);
  conv12q_kernel<<<2048, 256, 0, stream>>>(x, conv1_w, conv1_b, conv2_w, conv2_b,
                                           codebook, cnorm, quant, codes_f, codes_i);
  gruproj_kernel<<<64, 256, 0, stream>>>(PC, codes_i, gru_w_hh, gru_b_hh, proj_w, proj_b, pred);
}

// Round 11
// 1042.361 us; speedup vs baseline: 1.4350x; 1.0567x over previous
//
#include <hip/hip_runtime.h>

// Problem constants
#define NB   64      // batch
#define CIN  8
#define LIN  8192
#define L1N  4096    // conv1 out length
#define T2   2048    // conv2 out length (time steps)
#define ENC  64
#define NK   128     // codebook size
#define CD   64      // code dim
#define G3   192     // 3*ENC

// d_out layout (floats): quant_z [64*2048*64] | pred [64*2048*64] | codes [64*2048]
#define QOFF 0
#define POFF 8388608
#define COFF 16777216

// ws layout (floats): cnorm[128] @0 | PC[128*192] @128 | codes_i[131072] (int) @24704
#define PCOFF 128
#define CIOFF 24704

typedef _Float16 half2v __attribute__((ext_vector_type(2)));

__device__ __forceinline__ float sigf(float x) {
  float e = __builtin_amdgcn_exp2f(-1.4426950408889634f * x);
  return __builtin_amdgcn_rcpf(1.0f + e);
}
__device__ __forceinline__ float tanhf_fast(float x) {
  float e = __builtin_amdgcn_exp2f(2.8853900817779268f * x);
  return 1.0f - 2.0f * __builtin_amdgcn_rcpf(e + 1.0f);
}
__device__ __forceinline__ float rlane(float v, int k) {
  return __int_as_float(__builtin_amdgcn_readlane(__float_as_int(v), k));
}
__device__ __forceinline__ half2v as_h2(float v) { return __builtin_bit_cast(half2v, v); }

// ---------------- K0: prep = codebook norms (block 128) + PC table (blocks 0..127) ----------------
__global__ __launch_bounds__(192) void prep_kernel(const float* __restrict__ cb,
                                                   const float* __restrict__ w_ih,
                                                   const float* __restrict__ b_ih,
                                                   float* __restrict__ cnorm,
                                                   float* __restrict__ PC) {
  int blk = blockIdx.x;
  int j = threadIdx.x;
  if (blk == 128) {
    if (j < 128) {
      const float4* r = (const float4*)(cb + j * CD);
      float s0 = 0.f, s1 = 0.f, s2 = 0.f, s3 = 0.f;
#pragma unroll
      for (int q = 0; q < 16; q += 4) {
        float4 a = r[q], b = r[q + 1], cc = r[q + 2], d = r[q + 3];
        s0 += a.x * a.x + a.y * a.y + a.z * a.z + a.w * a.w;
        s1 += b.x * b.x + b.y * b.y + b.z * b.z + b.w * b.w;
        s2 += cc.x * cc.x + cc.y * cc.y + cc.z * cc.z + cc.w * cc.w;
        s3 += d.x * d.x + d.y * d.y + d.z * d.z + d.w * d.w;
      }
      cnorm[j] = (s0 + s1) + (s2 + s3);
    }
    return;
  }
  int c = blk;
  const float4* wp = (const float4*)(w_ih + j * ENC);
  const float4* cp = (const float4*)(cb + c * CD);
  float a0 = b_ih[j], a1 = 0.f, a2 = 0.f, a3 = 0.f;
#pragma unroll
  for (int q = 0; q < 16; q += 4) {
    float4 w0 = wp[q], c0 = cp[q];
    float4 w1 = wp[q + 1], c1 = cp[q + 1];
    float4 w2 = wp[q + 2], c2 = cp[q + 2];
    float4 w3 = wp[q + 3], c3 = cp[q + 3];
    a0 += w0.x * c0.x + w0.y * c0.y + w0.z * c0.z + w0.w * c0.w;
    a1 += w1.x * c1.x + w1.y * c1.y + w1.z * c1.z + w1.w * c1.w;
    a2 += w2.x * c2.x + w2.y * c2.y + w2.z * c2.z + w2.w * c2.w;
    a3 += w3.x * c3.x + w3.y * c3.y + w3.z * c3.z + w3.w * c3.w;
  }
  PC[c * G3 + j] = (a0 + a1) + (a2 + a3);
}

// ---------------- K1: FUSED conv1 + relu + conv2 + relu + VQ argmin + gather (R10, proven) ----------------
__global__ __launch_bounds__(256) void conv12q_kernel(const float* __restrict__ x,
                                                      const float* __restrict__ w1,
                                                      const float* __restrict__ b1,
                                                      const float* __restrict__ w2,
                                                      const float* __restrict__ b2,
                                                      const float* __restrict__ cb,
                                                      const float* __restrict__ cnorm,
                                                      float* __restrict__ quant,
                                                      float* __restrict__ codes_f,
                                                      int* __restrict__ codes_i) {
  __shared__ float sw2[32 * 5 * 64];     // 40960 B
  __shared__ float sw1[1280];            //  5120 B
  __shared__ float sy[32][136];          // 17408 B
  __shared__ float ubuf[4096];           // 16384 B : sxx[8][280] (phase A/B) then sz[64][64]
  float (*sxx)[280] = (float(*)[280])ubuf;
  float (*sz)[64]   = (float(*)[64])ubuf;
  int b = blockIdx.x >> 5;
  int t0 = (blockIdx.x & 31) * 64;
  int tid = threadIdx.x;

  // ---- phase A: stage x-tile + conv1 weights + conv2 weights ----
  for (int i = tid; i < 32 * 5 * 64; i += 256) {
    int co = i & 63, r = i >> 6;
    sw2[i] = w2[co * 160 + r];
  }
  for (int i = tid; i < 1280; i += 256) sw1[i] = w1[i];
  {
    const float* xb = x + b * CIN * LIN;
    int X0 = 4 * t0 - 10;
    for (int i = tid; i < 8 * 280; i += 256) {
      int ci = i / 280, xo = i - ci * 280;
      int xi = X0 + xo;
      sxx[ci][xo] = ((unsigned)xi < (unsigned)LIN) ? xb[ci * LIN + xi] : 0.f;
    }
  }
  __syncthreads();

  // ---- phase B: y1 window (conv1+relu), conv1's accumulation order (bias, ci, k) ----
  {
    int co1 = tid >> 3, sub = tid & 7;       // co1 in [0,32), 17 outputs per thread
    float acc1[17];
    float bias = b1[co1];
#pragma unroll
    for (int jj = 0; jj < 17; jj++) acc1[jj] = bias;
#pragma unroll 1
    for (int ci = 0; ci < 8; ci++) {
      float xv[38];
      const float2* s2 = (const float2*)(&sxx[ci][34 * sub]);
#pragma unroll
      for (int q = 0; q < 19; q++) {
        float2 v = s2[q];
        xv[2 * q] = v.x; xv[2 * q + 1] = v.y;
      }
      float wk1[5];
#pragma unroll
      for (int k = 0; k < 5; k++) wk1[k] = sw1[(co1 * 8 + ci) * 5 + k];
#pragma unroll
      for (int jj = 0; jj < 17; jj++) {
#pragma unroll
        for (int k = 0; k < 5; k++) acc1[jj] = fmaf(xv[2 * jj + k], wk1[k], acc1[jj]);
      }
    }
#pragma unroll
    for (int jj = 0; jj < 17; jj++) {
      int u = 17 * sub + jj;
      int p = 2 * t0 - 4 + u;                // y1 position
      sy[co1][u] = ((unsigned)p < (unsigned)L1N) ? fmaxf(acc1[jj], 0.f) : 0.f;
    }
  }
  __syncthreads();                            // sxx dead from here; ubuf becomes sz

  // ---- phase C: conv2 + relu into sz ----
  int co = tid & 63, ts = tid >> 6;
  {
    float acc[16];
    float bb = b2[co];
#pragma unroll
    for (int i = 0; i < 16; i++) acc[i] = bb;
    for (int ci = 0; ci < 32; ci++) {
      float xr[40];
      const float4* sx4 = (const float4*)(&sy[ci][32 * ts]);
#pragma unroll
      for (int q = 0; q < 10; q++) {
        float4 v = sx4[q];
        xr[4 * q] = v.x; xr[4 * q + 1] = v.y; xr[4 * q + 2] = v.z; xr[4 * q + 3] = v.w;
      }
      float wk[5];
#pragma unroll
      for (int k = 0; k < 5; k++) wk[k] = sw2[(ci * 5 + k) * 64 + co];
#pragma unroll
      for (int i = 0; i < 16; i++) {
#pragma unroll
        for (int k = 0; k < 5; k++) acc[i] = fmaf(xr[2 * i + k + 2], wk[k], acc[i]);
      }
    }
#pragma unroll
    for (int i = 0; i < 16; i++) sz[ts * 16 + i][co] = fmaxf(acc[i], 0.f);
  }
  __syncthreads();

  // ---- quant phase ----
  int lane = co, wave = ts;
  float4 ca[16], cq[16];
  {
    const float4* pa = (const float4*)(cb + lane * CD);
    const float4* pb = (const float4*)(cb + (64 + lane) * CD);
#pragma unroll
    for (int q = 0; q < 16; q++) { ca[q] = pa[q]; cq[q] = pb[q]; }
  }
  float cn0 = cnorm[lane], cn1 = cnorm[64 + lane];
  int vg0 = b * T2 + t0 + wave * 16;
  for (int i = 0; i < 16; i++) {
    int vl = wave * 16 + i;
    int v = vg0 + i;
    float d00 = 0.f, d01 = 0.f, d02 = 0.f, d03 = 0.f;
    float d10 = 0.f, d11 = 0.f, d12 = 0.f, d13 = 0.f;
#pragma unroll
    for (int q = 0; q < 16; q++) {
      float4 zq = *(const float4*)(&sz[vl][4 * q]);   // broadcast read, conflict-free
      d00 = fmaf(ca[q].x, zq.x, d00); d01 = fmaf(ca[q].y, zq.y, d01);
      d02 = fmaf(ca[q].z, zq.z, d02); d03 = fmaf(ca[q].w, zq.w, d03);
      d10 = fmaf(cq[q].x, zq.x, d10); d11 = fmaf(cq[q].y, zq.y, d11);
      d12 = fmaf(cq[q].z, zq.z, d12); d13 = fmaf(cq[q].w, zq.w, d13);
    }
    float s0 = cn0 - 2.f * ((d00 + d01) + (d02 + d03));
    float s1 = cn1 - 2.f * ((d10 + d11) + (d12 + d13));
    float sc; int idx;
    if (s1 < s0) { sc = s1; idx = 64 + lane; } else { sc = s0; idx = lane; }
#pragma unroll
    for (int m = 1; m < 64; m <<= 1) {
      float os = __shfl_xor(sc, m);
      int oi = __shfl_xor(idx, m);
      if (os < sc || (os == sc && oi < idx)) { sc = os; idx = oi; }
    }
    if (lane == 0) { codes_f[v] = (float)idx; codes_i[v] = idx; }
    quant[v * 64 + lane] = cb[idx * 64 + lane];
  }
}

// ---------------- K5: FUSED GRU scan + projection + wave-1 x-gather ----------------
// Wave 0 = proven single-wave f16-dot2 scan, but its per-step x-gather bookkeeping (code
// lookup, PC indexing, 3 gathered reads, 6-reg shift pipeline) moves to wave 1, which
// pre-resolves PC[code[t]] for chunk c+1 into a double-buffered xring during chunk c —
// synchronized by the chunk barriers that already exist. Wave 0's step is now just
// 3 linear ds_reads + pack + MV + tail (~10 fewer insts/step at the lone-wave cadence).
// Values read are bit-identical; scan math untouched. Waves 1-3 also project chunk c-1
// (as in the proven 806us version).
__global__ __attribute__((amdgpu_flat_work_group_size(256, 256), amdgpu_waves_per_eu(1, 1)))
void gruproj_kernel(const float* __restrict__ PC,
                    const int* __restrict__ codes_i,
                    const float* __restrict__ w_hh,
                    const float* __restrict__ b_hh,
                    const float* __restrict__ proj_w,
                    const float* __restrict__ proj_b,
                    float* __restrict__ pred) {
  __shared__ float pcl[NK * G3];         // 98304 B
  __shared__ int   cpl[T2];              //  8192 B
  __shared__ float hring[2][16][64];     //  8192 B
  __shared__ float xring[2][16][3][64];  // 24576 B  (total 139264 B)
  int b = blockIdx.x;
  int tid = threadIdx.x;
  int lane = tid & 63;
  int wq = tid >> 6;

  // stage this batch's codes + the PC table with all 256 threads
  {
    const int4* src = (const int4*)(codes_i + b * T2);
    int4* dst = (int4*)cpl;
    for (int f = tid; f < T2 / 4; f += 256) dst[f] = src[f];
    const float4* s2 = (const float4*)PC;
    float4* d2 = (float4*)pcl;
    for (int f = tid; f < NK * G3 / 4; f += 256) d2[f] = s2[f];
  }
  __syncthreads();

  // ---- per-role setup (wave-uniform branch) ----
  half2v wr[32], wz[32], wn[32];
  float br = 0.f, bz = 0.f, bn = 0.f;
  float hreg = 0.f;
  float4 w[16];
  float pbias = 0.f;

  if (wq == 0) {
    const float2* p0 = (const float2*)(w_hh + lane * ENC);
    const float2* p1 = (const float2*)(w_hh + (64 + lane) * ENC);
    const float2* p2 = (const float2*)(w_hh + (128 + lane) * ENC);
#pragma unroll
    for (int m = 0; m < 32; m++) {
      float2 a = p0[m]; wr[m] = (half2v){(_Float16)a.x, (_Float16)a.y};
      float2 c = p1[m]; wz[m] = (half2v){(_Float16)c.x, (_Float16)c.y};
      float2 d = p2[m]; wn[m] = (half2v){(_Float16)d.x, (_Float16)d.y};
    }
    br = b_hh[lane]; bz = b_hh[64 + lane]; bn = b_hh[128 + lane];
  } else {
    const float4* wp = (const float4*)(proj_w + lane * ENC);
#pragma unroll
    for (int q = 0; q < 16; q++) w[q] = wp[q];
    pbias = proj_b[lane];
    if (wq == 1) {
      // prologue: gather x rows for chunk 0 into xring[0]
#pragma unroll 1
      for (int i = 0; i < 16; i++) {
        int code = cpl[i];
        const float* g = pcl + code * G3;
        xring[0][i][0][lane] = g[lane];
        xring[0][i][1][lane] = g[64 + lane];
        xring[0][i][2][lane] = g[128 + lane];
      }
    }
  }
  __syncthreads();   // xring[0] ready for wave 0

  int lane2a = 2 * lane, lane2b = 2 * lane + 1;  // shuffle sources (loop-invariant)
  float* pbase = pred + (size_t)b * T2 * ENC + lane;

#pragma unroll 1
  for (int c = 0; c < 128; c++) {
    if (wq == 0) {
      // ---- 16 GRU steps using xring[c&1], writing h into hring[c&1] ----
      const float* xbuf = &xring[c & 1][0][0][0];
#pragma unroll 1
      for (int i = 0; i < 16; i++) {
        const float* xp = xbuf + i * 192;
        float xr = xp[lane], xz = xp[64 + lane], xn = xp[128 + lane];
        float he = __shfl(hreg, lane2a);
        float ho = __shfl(hreg, lane2b);
        half2v hp2 = {(_Float16)he, (_Float16)ho};
        float hpk = __builtin_bit_cast(float, hp2);
        float fr0 = br, fr1 = 0.f, fr2 = 0.f, fr3 = 0.f;
        float fz0 = bz, fz1 = 0.f, fz2 = 0.f, fz3 = 0.f;
        float fn0 = bn, fn1 = 0.f, fn2 = 0.f, fn3 = 0.f;
#define MV(q) { \
    float s0 = rlane(hpk, 4 * (q) + 0); float s1 = rlane(hpk, 4 * (q) + 1); \
    float s2 = rlane(hpk, 4 * (q) + 2); float s3 = rlane(hpk, 4 * (q) + 3); \
    fr0 = __builtin_amdgcn_fdot2(wr[4 * (q) + 0], as_h2(s0), fr0, false); \
    fr1 = __builtin_amdgcn_fdot2(wr[4 * (q) + 1], as_h2(s1), fr1, false); \
    fr2 = __builtin_amdgcn_fdot2(wr[4 * (q) + 2], as_h2(s2), fr2, false); \
    fr3 = __builtin_amdgcn_fdot2(wr[4 * (q) + 3], as_h2(s3), fr3, false); \
    fz0 = __builtin_amdgcn_fdot2(wz[4 * (q) + 0], as_h2(s0), fz0, false); \
    fz1 = __builtin_amdgcn_fdot2(wz[4 * (q) + 1], as_h2(s1), fz1, false); \
    fz2 = __builtin_amdgcn_fdot2(wz[4 * (q) + 2], as_h2(s2), fz2, false); \
    fz3 = __builtin_amdgcn_fdot2(wz[4 * (q) + 3], as_h2(s3), fz3, false); \
    fn0 = __builtin_amdgcn_fdot2(wn[4 * (q) + 0], as_h2(s0), fn0, false); \
    fn1 = __builtin_amdgcn_fdot2(wn[4 * (q) + 1], as_h2(s1), fn1, false); \
    fn2 = __builtin_amdgcn_fdot2(wn[4 * (q) + 2], as_h2(s2), fn2, false); \
    fn3 = __builtin_amdgcn_fdot2(wn[4 * (q) + 3], as_h2(s3), fn3, false); }
        MV(0) MV(1) MV(2) MV(3) MV(4) MV(5) MV(6) MV(7)
#undef MV
        float ghr = (fr0 + fr1) + (fr2 + fr3);
        float ghz = (fz0 + fz1) + (fz2 + fz3);
        float ghn = (fn0 + fn1) + (fn2 + fn3);
        float r = sigf(xr + ghr);
        float zg = sigf(xz + ghz);
        float n = tanhf_fast(xn + r * ghn);
        hreg = fmaf(zg, hreg - n, n);
        hring[c & 1][i][lane] = hreg;
      }
    } else {
      if (wq == 1 && c < 127) {
        // ---- gather x rows for chunk c+1 into xring[(c+1)&1] ----
        int tbase = (c + 1) * 16;
        float* xb2 = &xring[(c + 1) & 1][0][0][0];
#pragma unroll 1
        for (int i = 0; i < 16; i++) {
          int code = cpl[tbase + i];
          const float* g = pcl + code * G3;
          float* xo = xb2 + i * 192;
          xo[lane] = g[lane];
          xo[64 + lane] = g[64 + lane];
          xo[128 + lane] = g[128 + lane];
        }
      }
      if (c > 0) {
        // ---- project chunk c-1 from hring[(c-1)&1] ----
        int cc = c - 1, buf = cc & 1, tb = cc * 16;
#pragma unroll 1
        for (int t = wq - 1; t < 16; t += 3) {
          const float4* hrow = (const float4*)(&hring[buf][t][0]);   // broadcast reads
          float a0 = pbias, a1 = 0.f, a2 = 0.f, a3 = 0.f;
#pragma unroll
          for (int q = 0; q < 16; q += 4) {
            float4 ha = hrow[q], hb = hrow[q + 1], hc = hrow[q + 2], hd = hrow[q + 3];
            a0 += ha.x * w[q].x + ha.y * w[q].y + ha.z * w[q].z + ha.w * w[q].w;
            a1 += hb.x * w[q + 1].x + hb.y * w[q + 1].y + hb.z * w[q + 1].z + hb.w * w[q + 1].w;
            a2 += hc.x * w[q + 2].x + hc.y * w[q + 2].y + hc.z * w[q + 2].z + hc.w * w[q + 2].w;
            a3 += hd.x * w[q + 3].x + hd.y * w[q + 3].y + hd.z * w[q + 3].z + hd.w * w[q + 3].w;
          }
          pbase[(size_t)(tb + t) * ENC] = (a0 + a1) + (a2 + a3);
        }
      }
    }
    __syncthreads();
  }
  // ---- final chunk 127 ----
  if (wq > 0) {
    int buf = 127 & 1, tb = 127 * 16;
#pragma unroll 1
    for (int t = wq - 1; t < 16; t += 3) {
      const float4* hrow = (const float4*)(&hring[buf][t][0]);
      float a0 = pbias, a1 = 0.f, a2 = 0.f, a3 = 0.f;
#pragma unroll
      for (int q = 0; q < 16; q += 4) {
        float4 ha = hrow[q], hb = hrow[q + 1], hc = hrow[q + 2], hd = hrow[q + 3];
        a0 += ha.x * w[q].x + ha.y * w[q].y + ha.z * w[q].z + ha.w * w[q].w;
        a1 += hb.x * w[q + 1].x + hb.y * w[q + 1].y + hb.z * w[q + 1].z + hb.w * w[q + 1].w;
        a2 += hc.x * w[q + 2].x + hc.y * w[q + 2].y + hc.z * w[q + 2].z + hc.w * w[q + 2].w;
        a3 += hd.x * w[q + 3].x + hd.y * w[q + 3].y + hd.z * w[q + 3].z + hd.w * w[q + 3].w;
      }
      pbase[(size_t)(tb + t) * ENC] = (a0 + a1) + (a2 + a3);
    }
  }
}

extern "C" void kernel_launch(void* const* d_in, const int* in_sizes, int n_in,
                              void* d_out, int out_size, void* d_ws, size_t ws_size,
                              hipStream_t stream) {
  const float* x        = (const float*)d_in[0];
  const float* conv1_w  = (const float*)d_in[1];
  const float* conv1_b  = (const float*)d_in[2];
  const float* conv2_w  = (const float*)d_in[3];
  const float* conv2_b  = (const float*)d_in[4];
  const float* codebook = (const float*)d_in[5];
  const float* gru_w_ih = (const float*)d_in[6];
  const float* gru_w_hh = (const float*)d_in[7];
  const float* gru_b_ih = (const float*)d_in[8];
  const float* gru_b_hh = (const float*)d_in[9];
  const float* proj_w   = (const float*)d_in[10];
  const float* proj_b   = (const float*)d_in[11];

  float* out = (float*)d_out;
  float* quant = out + QOFF;     // quant_z output
  float* pred  = out + POFF;     // pred output
  float* codes_f = out + COFF;

  float* ws = (float*)d_ws;      // needs ~620 KB
  float* cnorm = ws;
  float* PC = ws + PCOFF;        // [128][192]
  int* codes_i = (int*)(ws + CIOFF);

  prep_kernel<<<129, 192, 0, stream>>>(codebook, gru_w_ih, gru_b_ih, cnorm, PC);
  conv12q_kernel<<<2048, 256, 0, stream>>>(x, conv1_w, conv1_b, conv2_w, conv2_b,
                                           codebook, cnorm, quant, codes_f, codes_i);
  gruproj_kernel<<<64, 256, 0, stream>>>(PC, codes_i, gru_w_hh, gru_b_hh, proj_w, proj_b, pred);
}